// Round 12
// baseline (396.075 us; speedup 1.0000x reference)
//
#include <hip/hip_runtime.h>
#include <hip/hip_cooperative_groups.h>
#include <stdint.h>

namespace cg = cooperative_groups;

// B=2, T=2048, C=1024, H=16, HD=64
// qkv ws layout: [3][B*H=32][T=2048][HD=64] bf16 (v region unused); vt: [32][64][2048] bf16

typedef short bf16x8 __attribute__((ext_vector_type(8)));
typedef float f32x4 __attribute__((ext_vector_type(4)));

__device__ inline unsigned short f2bf(float f) {
  union { float f; uint32_t u; } v; v.f = f;
  uint32_t u = v.u;
  u += 0x7FFFu + ((u >> 16) & 1u);   // round-to-nearest-even
  return (unsigned short)(u >> 16);
}

// pack two fp32 -> two bf16 in one dword — HW instruction (no builtin on gfx950, m240)
__device__ inline unsigned pkbf(float a, float b) {
  unsigned r;
  asm("v_cvt_pk_bf16_f32 %0, %1, %2" : "=v"(r) : "v"(a), "v"(b));
  return r;
}

// raw v_exp_f32 (2^x) without OCML range fixup; inputs bounded, -3e38 -> +0
__device__ inline float exp2_fast(float x) {
#if __has_builtin(__builtin_amdgcn_exp2f)
  return __builtin_amdgcn_exp2f(x);
#else
  float r; asm("v_exp_f32 %0, %1" : "=v"(r) : "v"(x)); return r;
#endif
}

// async global->LDS, 16B per lane, dest = lds base + lane*16
__device__ inline void load_lds16(const unsigned short* g, unsigned short* l) {
  __builtin_amdgcn_global_load_lds(
      (const __attribute__((address_space(1))) unsigned int*)(const void*)g,
      (__attribute__((address_space(3))) unsigned int*)(void*)l, 16, 0, 0);
}

// ============================================================================
// FUSED cooperative kernel: prep -> QKV -> attn -> proj with grid.sync between
// phases. Eliminates 3 inter-kernel launch gaps (~10us each). All four phase
// bodies are the round-11 proven kernels, byte-for-byte; only the block-index
// decode is remapped (grid-stride over work units).
// Grid 512 x 256thr: 2 blocks/CU co-resident (LDS 66KB attn-phase bound;
// launch_bounds(256,2) -> <=256 regs -> 8 waves/CU). QKV: 768 units over 512
// blocks = 96 slot-exec/CU (same as the r3 optimum's 3x32). attn: 512 exact.
// ============================================================================
__global__ __launch_bounds__(256, 2) void fused_all_kernel(
    const float* __restrict__ x, const float* __restrict__ w_attn,
    const float* __restrict__ bias_attn, const float* __restrict__ w_proj,
    const float* __restrict__ bias_proj, float* __restrict__ out,
    unsigned short* __restrict__ xb, unsigned short* __restrict__ wattnT,
    unsigned short* __restrict__ wprojT, unsigned short* __restrict__ qkvp,
    unsigned short* __restrict__ yb, unsigned short* __restrict__ vt) {
  // LDS union: prep tile (4.2KB) / QKV As+Bs (32KB) / attn Ks+Vs+Ps (66KB) / proj (16KB)
  __shared__ __align__(16) unsigned char smem[67584];
  cg::grid_group grid = cg::this_grid();
  const int bid = blockIdx.x;
  const int t = threadIdx.x;
  const int wave = t >> 6, lane = t & 63;
  const int L = lane & 15, quad = lane >> 4;

  // ---------------- phase 0: prep (cast x; transpose w_attn, w_proj) --------
  {
    float (*tile)[33] = reinterpret_cast<float(*)[33]>(smem);
    for (int u = bid; u < 8192; u += 512) {
      if (u < 4096) {
        int i = u * 256 + t;
        float4 f = reinterpret_cast<const float4*>(x)[i];
        ushort4 o;
        o.x = f2bf(f.x); o.y = f2bf(f.y); o.z = f2bf(f.z); o.w = f2bf(f.w);
        reinterpret_cast<ushort4*>(xb)[i] = o;
        continue;
      }
      const float* in; unsigned short* outp2; int R, Cn, bx, by;
      if (u < 7168) {
        int bb = u - 4096;
        in = w_attn; outp2 = wattnT; R = 1024; Cn = 3072;
        bx = (bb % 96) * 32; by = (bb / 96) * 32;
      } else {
        int bb = u - 7168;
        in = w_proj; outp2 = wprojT; R = 1024; Cn = 1024;
        bx = (bb % 32) * 32; by = (bb / 32) * 32;
      }
      const int tx = t & 31, ty = t >> 5;
      __syncthreads();                       // prior unit's tile fully read
      #pragma unroll
      for (int i = 0; i < 32; i += 8)
        tile[ty + i][tx] = in[(size_t)(by + ty + i) * Cn + bx + tx];
      __syncthreads();
      #pragma unroll
      for (int i = 0; i < 32; i += 8)
        outp2[(size_t)(bx + ty + i) * R + by + tx] = f2bf(tile[tx][ty + i]);
    }
  }
  grid.sync();

  // ---------------- phase 1: QKV GEMM (128x128, 2-buffer vmcnt(0)+barrier) --
  {
    constexpr int K = 1024;
    unsigned short (*As)[128 * 32] = reinterpret_cast<unsigned short(*)[128 * 32]>(smem);
    unsigned short (*Bs)[128 * 32] = reinterpret_cast<unsigned short(*)[128 * 32]>(smem + 16384);
    const int wm = (wave >> 1) * 64, wn = (wave & 1) * 64;
    const int drow = lane >> 2;
    const int dch  = (lane & 3) ^ ((drow >> 1) & 3);
    const int foff = ((quad ^ ((L >> 1) & 3)) * 8);

    for (int u = bid; u < 768; u += 512) {
      const int m0 = (u / 24) * 128, n0 = (u % 24) * 128;
      const unsigned short* Ab = xb     + (size_t)(m0 + wave * 32 + drow) * K + dch * 8;
      const unsigned short* Bb = wattnT + (size_t)(n0 + wave * 32 + drow) * K + dch * 8;
      f32x4 acc[4][4] = {};

      #pragma unroll
      for (int j = 0; j < 2; ++j) {
        load_lds16(Ab + (size_t)j * 16 * K, &As[0][(wave * 32 + j * 16) * 32]);
        load_lds16(Bb + (size_t)j * 16 * K, &Bs[0][(wave * 32 + j * 16) * 32]);
      }
      int buf = 0;
      for (int kt = 0; kt < 32; ++kt) {
        asm volatile("" ::: "memory");
        __builtin_amdgcn_s_waitcnt(0x0F70);   // vmcnt(0)
        __builtin_amdgcn_s_barrier();
        asm volatile("" ::: "memory");
        if (kt + 1 < 32) {
          #pragma unroll
          for (int j = 0; j < 2; ++j) {
            load_lds16(Ab + (size_t)j * 16 * K + (kt + 1) * 32,
                       &As[buf ^ 1][(wave * 32 + j * 16) * 32]);
            load_lds16(Bb + (size_t)j * 16 * K + (kt + 1) * 32,
                       &Bs[buf ^ 1][(wave * 32 + j * 16) * 32]);
          }
        }
        bf16x8 af[4], bf[4];
        #pragma unroll
        for (int mt = 0; mt < 4; ++mt)
          af[mt] = *reinterpret_cast<const bf16x8*>(&As[buf][(wm + mt * 16 + L) * 32 + foff]);
        #pragma unroll
        for (int nt = 0; nt < 4; ++nt)
          bf[nt] = *reinterpret_cast<const bf16x8*>(&Bs[buf][(wn + nt * 16 + L) * 32 + foff]);
        __builtin_amdgcn_s_setprio(1);
        #pragma unroll
        for (int mt = 0; mt < 4; ++mt)
          #pragma unroll
          for (int nt = 0; nt < 4; ++nt)
            acc[mt][nt] = __builtin_amdgcn_mfma_f32_16x16x32_bf16(af[mt], bf[nt], acc[mt][nt], 0, 0, 0);
        __builtin_amdgcn_s_setprio(0);
        buf ^= 1;
      }
      // epilogue: QKV scatter (q scaled by 0.125*log2e), v -> vt[bh][d][t]
      #pragma unroll
      for (int mt = 0; mt < 4; ++mt)
        #pragma unroll
        for (int nt = 0; nt < 4; ++nt) {
          int col = n0 + wn + nt * 16 + L;
          int sel = col >> 10, cc = col & 1023;
          int h = cc >> 6, d = cc & 63;
          float b = bias_attn[col];
          float sc = (sel == 0) ? 0.18033688011112042f : 1.0f;
          #pragma unroll
          for (int r = 0; r < 4; ++r) {
            int row = m0 + wm + mt * 16 + quad * 4 + r;
            int bb = row >> 11, tt = row & 2047;
            float val = (acc[mt][nt][r] + b) * sc;
            if (sel == 2) {
              vt[((size_t)(bb * 16 + h) * 64 + d) * 2048 + tt] = f2bf(val);
            } else {
              qkvp[(((size_t)sel * 32 + (size_t)(bb * 16 + h)) * 2048 + tt) * 64 + d] = f2bf(val);
            }
          }
        }
    }
  }
  grid.sync();

  // ---------------- phase 2: flash attention v5 (512 units, 1:1) ------------
  {
    unsigned short (*Ks)[64 * 64] = reinterpret_cast<unsigned short(*)[64 * 64]>(smem);
    unsigned short (*Vs)[64 * 64] = reinterpret_cast<unsigned short(*)[64 * 64]>(smem + 24576);
    unsigned short (*Ps)[32][72]  = reinterpret_cast<unsigned short(*)[32][72]>(smem + 49152);

    const int b = bid;
    const int bh = (b & 7) * 4 + ((b >> 3) & 3);
    const int pi = b >> 5;
    const int tA = pi, tB = 31 - pi;
    const int rowA0 = tA * 64 + wave * 16;
    const int rowB0 = tB * 64 + wave * 16;
    const int ntiles = tB + 1;

    const unsigned short* qb  = qkvp + ((size_t)bh * 2048) * 64;
    const unsigned short* kb  = qkvp + ((size_t)(32 + bh) * 2048) * 64;
    const unsigned short* vtb = vt + (size_t)bh * 64 * 2048;

    const int drow = lane >> 3;
    const int dch  = (lane & 7) ^ drow;
    const int fo0 = ((quad ^ (L & 7)) * 8);
    const int fo1 = (((quad + 4) ^ (L & 7)) * 8);

    bf16x8 qfA[2], qfB[2];
    #pragma unroll
    for (int h = 0; h < 2; ++h) {
      qfA[h] = *reinterpret_cast<const bf16x8*>(qb + (size_t)(rowA0 + L) * 64 + h * 32 + quad * 8);
      qfB[h] = *reinterpret_cast<const bf16x8*>(qb + (size_t)(rowB0 + L) * 64 + h * 32 + quad * 8);
    }

    f32x4 oA[4] = {}, oB[4] = {};
    float rsA = 0.f, rsB = 0.f;

    #pragma unroll
    for (int j = 0; j < 2; ++j) {
      int r0 = wave * 16 + j * 8;
      load_lds16(kb  + (size_t)(r0 + drow) * 64 + dch * 8, &Ks[0][r0 * 64]);
      load_lds16(vtb + (size_t)(r0 + drow) * 2048 + dch * 8, &Vs[0][r0 * 64]);
    }

    int buf = 0;
    for (int kt = 0; kt < ntiles; ++kt) {
      const int nkt = (kt + 1 < ntiles) ? kt + 1 : ntiles - 1;
      const int nbuf = (buf == 2) ? 0 : buf + 1;
      {
        const int kg = nkt * 64;
        #pragma unroll
        for (int j = 0; j < 2; ++j) {
          int r0 = wave * 16 + j * 8;
          load_lds16(kb  + (size_t)(kg + r0 + drow) * 64 + dch * 8, &Ks[nbuf][r0 * 64]);
          load_lds16(vtb + (size_t)(r0 + drow) * 2048 + kg + dch * 8, &Vs[nbuf][r0 * 64]);
        }
      }
      asm volatile("" ::: "memory");
      __builtin_amdgcn_s_waitcnt(0x0F74);   // vmcnt(4)
      __builtin_amdgcn_s_barrier();
      asm volatile("" ::: "memory");

      const bool actA = (kt <= tA);

      bf16x8 kf[4][2];
      #pragma unroll
      for (int nt = 0; nt < 4; ++nt) {
        kf[nt][0] = *reinterpret_cast<const bf16x8*>(&Ks[buf][(nt * 16 + L) * 64 + fo0]);
        kf[nt][1] = *reinterpret_cast<const bf16x8*>(&Ks[buf][(nt * 16 + L) * 64 + fo1]);
      }

      f32x4 sB[4] = {};
      __builtin_amdgcn_s_setprio(1);
      #pragma unroll
      for (int nt = 0; nt < 4; ++nt) {
        sB[nt] = __builtin_amdgcn_mfma_f32_16x16x32_bf16(kf[nt][0], qfB[0], sB[nt], 0, 0, 0);
        sB[nt] = __builtin_amdgcn_mfma_f32_16x16x32_bf16(kf[nt][1], qfB[1], sB[nt], 0, 0, 0);
      }
      __builtin_amdgcn_s_setprio(0);
      if (kt == tB) {
        #pragma unroll
        for (int nt = 0; nt < 4; ++nt) {
          int key0 = kt * 64 + nt * 16 + quad * 4;
          int qr = rowB0 + L;
          #pragma unroll
          for (int r = 0; r < 4; ++r)
            if (key0 + r > qr) sB[nt][r] = -3.0e38f;
        }
      }
      #pragma unroll
      for (int nt = 0; nt < 4; ++nt) {
        float p0 = exp2_fast(sB[nt][0]), p1 = exp2_fast(sB[nt][1]);
        float p2 = exp2_fast(sB[nt][2]), p3 = exp2_fast(sB[nt][3]);
        rsB += (p0 + p1) + (p2 + p3);
        uint2 pk;
        pk.x = pkbf(p0, p1);
        pk.y = pkbf(p2, p3);
        *reinterpret_cast<uint2*>(&Ps[wave][16 + L][nt * 16 + quad * 4]) = pk;
      }

      if (actA) {
        f32x4 sA[4] = {};
        __builtin_amdgcn_s_setprio(1);
        #pragma unroll
        for (int nt = 0; nt < 4; ++nt) {
          sA[nt] = __builtin_amdgcn_mfma_f32_16x16x32_bf16(kf[nt][0], qfA[0], sA[nt], 0, 0, 0);
          sA[nt] = __builtin_amdgcn_mfma_f32_16x16x32_bf16(kf[nt][1], qfA[1], sA[nt], 0, 0, 0);
        }
        __builtin_amdgcn_s_setprio(0);
        if (kt == tA) {
          #pragma unroll
          for (int nt = 0; nt < 4; ++nt) {
            int key0 = kt * 64 + nt * 16 + quad * 4;
            int qr = rowA0 + L;
            #pragma unroll
            for (int r = 0; r < 4; ++r)
              if (key0 + r > qr) sA[nt][r] = -3.0e38f;
          }
        }
        #pragma unroll
        for (int nt = 0; nt < 4; ++nt) {
          float p0 = exp2_fast(sA[nt][0]), p1 = exp2_fast(sA[nt][1]);
          float p2 = exp2_fast(sA[nt][2]), p3 = exp2_fast(sA[nt][3]);
          rsA += (p0 + p1) + (p2 + p3);
          uint2 pk;
          pk.x = pkbf(p0, p1);
          pk.y = pkbf(p2, p3);
          *reinterpret_cast<uint2*>(&Ps[wave][L][nt * 16 + quad * 4]) = pk;
        }
      }

      bf16x8 vf[4][2];
      #pragma unroll
      for (int nt = 0; nt < 4; ++nt) {
        vf[nt][0] = *reinterpret_cast<const bf16x8*>(&Vs[buf][(nt * 16 + L) * 64 + fo0]);
        vf[nt][1] = *reinterpret_cast<const bf16x8*>(&Vs[buf][(nt * 16 + L) * 64 + fo1]);
      }
      bf16x8 pb0 = *reinterpret_cast<const bf16x8*>(&Ps[wave][16 + L][quad * 8]);
      bf16x8 pb1 = *reinterpret_cast<const bf16x8*>(&Ps[wave][16 + L][32 + quad * 8]);
      __builtin_amdgcn_s_setprio(1);
      #pragma unroll
      for (int nt = 0; nt < 4; ++nt) {
        oB[nt] = __builtin_amdgcn_mfma_f32_16x16x32_bf16(pb0, vf[nt][0], oB[nt], 0, 0, 0);
        oB[nt] = __builtin_amdgcn_mfma_f32_16x16x32_bf16(pb1, vf[nt][1], oB[nt], 0, 0, 0);
      }
      __builtin_amdgcn_s_setprio(0);
      if (actA) {
        bf16x8 pa0 = *reinterpret_cast<const bf16x8*>(&Ps[wave][L][quad * 8]);
        bf16x8 pa1 = *reinterpret_cast<const bf16x8*>(&Ps[wave][L][32 + quad * 8]);
        __builtin_amdgcn_s_setprio(1);
        #pragma unroll
        for (int nt = 0; nt < 4; ++nt) {
          oA[nt] = __builtin_amdgcn_mfma_f32_16x16x32_bf16(pa0, vf[nt][0], oA[nt], 0, 0, 0);
          oA[nt] = __builtin_amdgcn_mfma_f32_16x16x32_bf16(pa1, vf[nt][1], oA[nt], 0, 0, 0);
        }
        __builtin_amdgcn_s_setprio(0);
      }
      buf = nbuf;
    }

    float a = rsA; a += __shfl_xor(a, 16, 64); a += __shfl_xor(a, 32, 64);
    float b2 = rsB; b2 += __shfl_xor(b2, 16, 64); b2 += __shfl_xor(b2, 32, 64);
    float invA[4], invB[4];
    #pragma unroll
    for (int r = 0; r < 4; ++r) {
      invA[r] = 1.0f / __shfl(a, quad * 4 + r, 64);
      invB[r] = 1.0f / __shfl(b2, quad * 4 + r, 64);
    }
    const int bb = bh >> 4, hh = bh & 15;
    #pragma unroll
    for (int nt = 0; nt < 4; ++nt)
      #pragma unroll
      for (int r = 0; r < 4; ++r) {
        int rA = rowA0 + quad * 4 + r;
        int rB = rowB0 + quad * 4 + r;
        int col = hh * 64 + nt * 16 + L;
        yb[((size_t)bb * 2048 + rA) * 1024 + col] = f2bf(oA[nt][r] * invA[r]);
        yb[((size_t)bb * 2048 + rB) * 1024 + col] = f2bf(oB[nt][r] * invB[r]);
      }
    __builtin_amdgcn_s_waitcnt(0);   // drain dummy DMAs before LDS reuse
  }
  grid.sync();

  // ---------------- phase 3: proj GEMM (64x64, 1024 units, 2/block) ---------
  {
    constexpr int K = 1024;
    unsigned short (*As)[64 * 32] = reinterpret_cast<unsigned short(*)[64 * 32]>(smem);
    unsigned short (*Bs)[64 * 32] = reinterpret_cast<unsigned short(*)[64 * 32]>(smem + 8192);
    const int wm = (wave >> 1) * 32, wn = (wave & 1) * 32;
    const int drow = lane >> 2;
    const int dch  = (lane & 3) ^ ((drow >> 1) & 3);
    const int foff = ((quad ^ ((L >> 1) & 3)) * 8);

    for (int u = bid; u < 1024; u += 512) {
      const int m0 = (u >> 4) * 64, n0 = (u & 15) * 64;
      const unsigned short* Ab = yb     + (size_t)(m0 + wave * 16 + drow) * K + dch * 8;
      const unsigned short* Bb = wprojT + (size_t)(n0 + wave * 16 + drow) * K + dch * 8;
      f32x4 acc[2][2] = {};

      load_lds16(Ab, &As[0][(wave * 16) * 32]);
      load_lds16(Bb, &Bs[0][(wave * 16) * 32]);
      int buf = 0;
      for (int kt = 0; kt < 32; ++kt) {
        asm volatile("" ::: "memory");
        __builtin_amdgcn_s_waitcnt(0x0F70);
        __builtin_amdgcn_s_barrier();
        asm volatile("" ::: "memory");
        if (kt + 1 < 32) {
          load_lds16(Ab + (kt + 1) * 32, &As[buf ^ 1][(wave * 16) * 32]);
          load_lds16(Bb + (kt + 1) * 32, &Bs[buf ^ 1][(wave * 16) * 32]);
        }
        bf16x8 af[2], bf[2];
        #pragma unroll
        for (int mt = 0; mt < 2; ++mt)
          af[mt] = *reinterpret_cast<const bf16x8*>(&As[buf][(wm + mt * 16 + L) * 32 + foff]);
        #pragma unroll
        for (int nt = 0; nt < 2; ++nt)
          bf[nt] = *reinterpret_cast<const bf16x8*>(&Bs[buf][(wn + nt * 16 + L) * 32 + foff]);
        __builtin_amdgcn_s_setprio(1);
        #pragma unroll
        for (int mt = 0; mt < 2; ++mt)
          #pragma unroll
          for (int nt = 0; nt < 2; ++nt)
            acc[mt][nt] = __builtin_amdgcn_mfma_f32_16x16x32_bf16(af[mt], bf[nt], acc[mt][nt], 0, 0, 0);
        __builtin_amdgcn_s_setprio(0);
        buf ^= 1;
      }
      #pragma unroll
      for (int mt = 0; mt < 2; ++mt)
        #pragma unroll
        for (int nt = 0; nt < 2; ++nt) {
          int col = n0 + wn + nt * 16 + L;
          float b = bias_proj[col];
          #pragma unroll
          for (int r = 0; r < 4; ++r) {
            int row = m0 + wm + mt * 16 + quad * 4 + r;
            out[(size_t)row * 1024 + col] = acc[mt][nt][r] + b;
          }
        }
    }
  }
}

// ============================================================================
// Fallback path: the round-11 proven 4-launch pipeline (used if cooperative
// launch is rejected, e.g. by graph capture).
// ============================================================================
__global__ __launch_bounds__(256) void prep_kernel(
    const float* __restrict__ x, const float* __restrict__ w_attn,
    const float* __restrict__ w_proj,
    unsigned short* __restrict__ xb, unsigned short* __restrict__ wattnT,
    unsigned short* __restrict__ wprojT) {
  __shared__ float tile[32][33];
  const int b = blockIdx.x, t = threadIdx.x;
  if (b < 4096) {
    int i = b * 256 + t;
    float4 f = reinterpret_cast<const float4*>(x)[i];
    ushort4 o;
    o.x = f2bf(f.x); o.y = f2bf(f.y); o.z = f2bf(f.z); o.w = f2bf(f.w);
    reinterpret_cast<ushort4*>(xb)[i] = o;
    return;
  }
  const float* in; unsigned short* out; int R, Cn, bx, by;
  if (b < 7168) {
    int bb = b - 4096;
    in = w_attn; out = wattnT; R = 1024; Cn = 3072;
    bx = (bb % 96) * 32; by = (bb / 96) * 32;
  } else {
    int bb = b - 7168;
    in = w_proj; out = wprojT; R = 1024; Cn = 1024;
    bx = (bb % 32) * 32; by = (bb / 32) * 32;
  }
  const int tx = t & 31, ty = t >> 5;
  #pragma unroll
  for (int i = 0; i < 32; i += 8)
    tile[ty + i][tx] = in[(size_t)(by + ty + i) * Cn + bx + tx];
  __syncthreads();
  #pragma unroll
  for (int i = 0; i < 32; i += 8)
    out[(size_t)(bx + ty + i) * R + by + tx] = f2bf(tile[tx][ty + i]);
}

template<int BM, int BN>
__global__ __launch_bounds__(256) void gemm_bt_kernel(
    const unsigned short* __restrict__ A,
    const unsigned short* __restrict__ Bt,
    const float* __restrict__ bias,
    void* __restrict__ outp,
    unsigned short* __restrict__ vtp,
    int M, int N, int K, int mode) {
  constexpr int MT = BM / 32, NT = BN / 32;
  constexpr int RPWA = BM / 4, RPWB = BN / 4;
  constexpr int NJA = RPWA / 16, NJB = RPWB / 16;
  __shared__ unsigned short As[2][BM * 32];
  __shared__ unsigned short Bs[2][BN * 32];
  const int t = threadIdx.x;
  const int wave = t >> 6, lane = t & 63;
  const int L = lane & 15, quad = lane >> 4;
  const int wm = (wave >> 1) * (BM / 2), wn = (wave & 1) * (BN / 2);
  const int m0 = blockIdx.y * BM, n0 = blockIdx.x * BN;

  const int drow = lane >> 2;
  const int dch  = (lane & 3) ^ ((drow >> 1) & 3);
  const int foff = ((quad ^ ((L >> 1) & 3)) * 8);

  const unsigned short* Ab = A  + (size_t)(m0 + wave * RPWA + drow) * K + dch * 8;
  const unsigned short* Bb = Bt + (size_t)(n0 + wave * RPWB + drow) * K + dch * 8;

  f32x4 acc[MT][NT] = {};
  const int NK = K >> 5;

  #pragma unroll
  for (int j = 0; j < NJA; ++j)
    load_lds16(Ab + (size_t)j * 16 * K, &As[0][(wave * RPWA + j * 16) * 32]);
  #pragma unroll
  for (int j = 0; j < NJB; ++j)
    load_lds16(Bb + (size_t)j * 16 * K, &Bs[0][(wave * RPWB + j * 16) * 32]);

  int buf = 0;
  for (int kt = 0; kt < NK; ++kt) {
    asm volatile("" ::: "memory");
    __builtin_amdgcn_s_waitcnt(0x0F70);
    __builtin_amdgcn_s_barrier();
    asm volatile("" ::: "memory");

    if (kt + 1 < NK) {
      #pragma unroll
      for (int j = 0; j < NJA; ++j)
        load_lds16(Ab + (size_t)j * 16 * K + (kt + 1) * 32,
                   &As[buf ^ 1][(wave * RPWA + j * 16) * 32]);
      #pragma unroll
      for (int j = 0; j < NJB; ++j)
        load_lds16(Bb + (size_t)j * 16 * K + (kt + 1) * 32,
                   &Bs[buf ^ 1][(wave * RPWB + j * 16) * 32]);
    }

    bf16x8 af[MT], bf[NT];
    #pragma unroll
    for (int mt = 0; mt < MT; ++mt)
      af[mt] = *reinterpret_cast<const bf16x8*>(&As[buf][(wm + mt * 16 + L) * 32 + foff]);
    #pragma unroll
    for (int nt = 0; nt < NT; ++nt)
      bf[nt] = *reinterpret_cast<const bf16x8*>(&Bs[buf][(wn + nt * 16 + L) * 32 + foff]);
    __builtin_amdgcn_s_setprio(1);
    #pragma unroll
    for (int mt = 0; mt < MT; ++mt)
      #pragma unroll
      for (int nt = 0; nt < NT; ++nt)
        acc[mt][nt] = __builtin_amdgcn_mfma_f32_16x16x32_bf16(af[mt], bf[nt], acc[mt][nt], 0, 0, 0);
    __builtin_amdgcn_s_setprio(0);
    buf ^= 1;
  }

  if (mode == 0) {
    float* out = (float*)outp;
    #pragma unroll
    for (int mt = 0; mt < MT; ++mt)
      #pragma unroll
      for (int nt = 0; nt < NT; ++nt) {
        int col = n0 + wn + nt * 16 + L;
        float b = bias[col];
        #pragma unroll
        for (int r = 0; r < 4; ++r) {
          int row = m0 + wm + mt * 16 + quad * 4 + r;
          out[(size_t)row * N + col] = acc[mt][nt][r] + b;
        }
      }
  } else {
    unsigned short* qkv = (unsigned short*)outp;
    #pragma unroll
    for (int mt = 0; mt < MT; ++mt)
      #pragma unroll
      for (int nt = 0; nt < NT; ++nt) {
        int col = n0 + wn + nt * 16 + L;
        int sel = col >> 10, cc = col & 1023;
        int h = cc >> 6, d = cc & 63;
        float b = bias[col];
        float sc = (sel == 0) ? 0.18033688011112042f : 1.0f;
        #pragma unroll
        for (int r = 0; r < 4; ++r) {
          int row = m0 + wm + mt * 16 + quad * 4 + r;
          int bb = row >> 11, tt = row & 2047;
          float val = (acc[mt][nt][r] + b) * sc;
          if (sel == 2) {
            vtp[((size_t)(bb * 16 + h) * 64 + d) * 2048 + tt] = f2bf(val);
          } else {
            qkv[(((size_t)sel * 32 + (size_t)(bb * 16 + h)) * 2048 + tt) * 64 + d] = f2bf(val);
          }
        }
      }
  }
}

__global__ __launch_bounds__(256) void attn_kernel(
    const unsigned short* __restrict__ qkv,
    const unsigned short* __restrict__ vt,
    unsigned short* __restrict__ y) {
  __shared__ unsigned short Ks[3][64 * 64];
  __shared__ unsigned short Vs[3][64 * 64];
  __shared__ unsigned short Ps[4][32][72];

  const int t = threadIdx.x;
  const int wave = t >> 6, lane = t & 63;
  const int L = lane & 15, quad = lane >> 4;
  const int b = blockIdx.x;
  const int bh = (b & 7) * 4 + ((b >> 3) & 3);
  const int pi = b >> 5;
  const int tA = pi, tB = 31 - pi;
  const int rowA0 = tA * 64 + wave * 16;
  const int rowB0 = tB * 64 + wave * 16;
  const int ntiles = tB + 1;

  const unsigned short* qb  = qkv + ((size_t)bh * 2048) * 64;
  const unsigned short* kb  = qkv + ((size_t)(32 + bh) * 2048) * 64;
  const unsigned short* vtb = vt + (size_t)bh * 64 * 2048;

  const int drow = lane >> 3;
  const int dch  = (lane & 7) ^ drow;
  const int fo0 = ((quad ^ (L & 7)) * 8);
  const int fo1 = (((quad + 4) ^ (L & 7)) * 8);

  bf16x8 qfA[2], qfB[2];
  #pragma unroll
  for (int h = 0; h < 2; ++h) {
    qfA[h] = *reinterpret_cast<const bf16x8*>(qb + (size_t)(rowA0 + L) * 64 + h * 32 + quad * 8);
    qfB[h] = *reinterpret_cast<const bf16x8*>(qb + (size_t)(rowB0 + L) * 64 + h * 32 + quad * 8);
  }

  f32x4 oA[4] = {}, oB[4] = {};
  float rsA = 0.f, rsB = 0.f;

  {
    #pragma unroll
    for (int j = 0; j < 2; ++j) {
      int r0 = wave * 16 + j * 8;
      load_lds16(kb  + (size_t)(0 + r0 + drow) * 64 + dch * 8, &Ks[0][r0 * 64]);
      load_lds16(vtb + (size_t)(r0 + drow) * 2048 + 0 + dch * 8, &Vs[0][r0 * 64]);
    }
  }

  int buf = 0;
  for (int kt = 0; kt < ntiles; ++kt) {
    const int nkt = (kt + 1 < ntiles) ? kt + 1 : ntiles - 1;
    const int nbuf = (buf == 2) ? 0 : buf + 1;
    {
      const int kg = nkt * 64;
      #pragma unroll
      for (int j = 0; j < 2; ++j) {
        int r0 = wave * 16 + j * 8;
        load_lds16(kb  + (size_t)(kg + r0 + drow) * 64 + dch * 8, &Ks[nbuf][r0 * 64]);
        load_lds16(vtb + (size_t)(r0 + drow) * 2048 + kg + dch * 8, &Vs[nbuf][r0 * 64]);
      }
    }
    asm volatile("" ::: "memory");
    __builtin_amdgcn_s_waitcnt(0x0F74);
    __builtin_amdgcn_s_barrier();
    asm volatile("" ::: "memory");

    const bool actA = (kt <= tA);

    bf16x8 kf[4][2];
    #pragma unroll
    for (int nt = 0; nt < 4; ++nt) {
      kf[nt][0] = *reinterpret_cast<const bf16x8*>(&Ks[buf][(nt * 16 + L) * 64 + fo0]);
      kf[nt][1] = *reinterpret_cast<const bf16x8*>(&Ks[buf][(nt * 16 + L) * 64 + fo1]);
    }

    f32x4 sB[4] = {};
    __builtin_amdgcn_s_setprio(1);
    #pragma unroll
    for (int nt = 0; nt < 4; ++nt) {
      sB[nt] = __builtin_amdgcn_mfma_f32_16x16x32_bf16(kf[nt][0], qfB[0], sB[nt], 0, 0, 0);
      sB[nt] = __builtin_amdgcn_mfma_f32_16x16x32_bf16(kf[nt][1], qfB[1], sB[nt], 0, 0, 0);
    }
    __builtin_amdgcn_s_setprio(0);
    if (kt == tB) {
      #pragma unroll
      for (int nt = 0; nt < 4; ++nt) {
        int key0 = kt * 64 + nt * 16 + quad * 4;
        int qr = rowB0 + L;
        #pragma unroll
        for (int r = 0; r < 4; ++r)
          if (key0 + r > qr) sB[nt][r] = -3.0e38f;
      }
    }
    #pragma unroll
    for (int nt = 0; nt < 4; ++nt) {
      float p0 = exp2_fast(sB[nt][0]), p1 = exp2_fast(sB[nt][1]);
      float p2 = exp2_fast(sB[nt][2]), p3 = exp2_fast(sB[nt][3]);
      rsB += (p0 + p1) + (p2 + p3);
      uint2 pk;
      pk.x = pkbf(p0, p1);
      pk.y = pkbf(p2, p3);
      *reinterpret_cast<uint2*>(&Ps[wave][16 + L][nt * 16 + quad * 4]) = pk;
    }

    if (actA) {
      f32x4 sA[4] = {};
      __builtin_amdgcn_s_setprio(1);
      #pragma unroll
      for (int nt = 0; nt < 4; ++nt) {
        sA[nt] = __builtin_amdgcn_mfma_f32_16x16x32_bf16(kf[nt][0], qfA[0], sA[nt], 0, 0, 0);
        sA[nt] = __builtin_amdgcn_mfma_f32_16x16x32_bf16(kf[nt][1], qfA[1], sA[nt], 0, 0, 0);
      }
      __builtin_amdgcn_s_setprio(0);
      if (kt == tA) {
        #pragma unroll
        for (int nt = 0; nt < 4; ++nt) {
          int key0 = kt * 64 + nt * 16 + quad * 4;
          int qr = rowA0 + L;
          #pragma unroll
          for (int r = 0; r < 4; ++r)
            if (key0 + r > qr) sA[nt][r] = -3.0e38f;
        }
      }
      #pragma unroll
      for (int nt = 0; nt < 4; ++nt) {
        float p0 = exp2_fast(sA[nt][0]), p1 = exp2_fast(sA[nt][1]);
        float p2 = exp2_fast(sA[nt][2]), p3 = exp2_fast(sA[nt][3]);
        rsA += (p0 + p1) + (p2 + p3);
        uint2 pk;
        pk.x = pkbf(p0, p1);
        pk.y = pkbf(p2, p3);
        *reinterpret_cast<uint2*>(&Ps[wave][L][nt * 16 + quad * 4]) = pk;
      }
    }

    bf16x8 vf[4][2];
    #pragma unroll
    for (int nt = 0; nt < 4; ++nt) {
      vf[nt][0] = *reinterpret_cast<const bf16x8*>(&Vs[buf][(nt * 16 + L) * 64 + fo0]);
      vf[nt][1] = *reinterpret_cast<const bf16x8*>(&Vs[buf][(nt * 16 + L) * 64 + fo1]);
    }
    bf16x8 pb0 = *reinterpret_cast<const bf16x8*>(&Ps[wave][16 + L][quad * 8]);
    bf16x8 pb1 = *reinterpret_cast<const bf16x8*>(&Ps[wave][16 + L][32 + quad * 8]);
    __builtin_amdgcn_s_setprio(1);
    #pragma unroll
    for (int nt = 0; nt < 4; ++nt) {
      oB[nt] = __builtin_amdgcn_mfma_f32_16x16x32_bf16(pb0, vf[nt][0], oB[nt], 0, 0, 0);
      oB[nt] = __builtin_amdgcn_mfma_f32_16x16x32_bf16(pb1, vf[nt][1], oB[nt], 0, 0, 0);
    }
    __builtin_amdgcn_s_setprio(0);
    if (actA) {
      bf16x8 pa0 = *reinterpret_cast<const bf16x8*>(&Ps[wave][L][quad * 8]);
      bf16x8 pa1 = *reinterpret_cast<const bf16x8*>(&Ps[wave][L][32 + quad * 8]);
      __builtin_amdgcn_s_setprio(1);
      #pragma unroll
      for (int nt = 0; nt < 4; ++nt) {
        oA[nt] = __builtin_amdgcn_mfma_f32_16x16x32_bf16(pa0, vf[nt][0], oA[nt], 0, 0, 0);
        oA[nt] = __builtin_amdgcn_mfma_f32_16x16x32_bf16(pa1, vf[nt][1], oA[nt], 0, 0, 0);
      }
      __builtin_amdgcn_s_setprio(0);
    }
    buf = nbuf;
  }

  float a = rsA; a += __shfl_xor(a, 16, 64); a += __shfl_xor(a, 32, 64);
  float b2 = rsB; b2 += __shfl_xor(b2, 16, 64); b2 += __shfl_xor(b2, 32, 64);
  float invA[4], invB[4];
  #pragma unroll
  for (int r = 0; r < 4; ++r) {
    invA[r] = 1.0f / __shfl(a, quad * 4 + r, 64);
    invB[r] = 1.0f / __shfl(b2, quad * 4 + r, 64);
  }
  const int bb = bh >> 4, hh = bh & 15;
  #pragma unroll
  for (int nt = 0; nt < 4; ++nt)
    #pragma unroll
    for (int r = 0; r < 4; ++r) {
      int rA = rowA0 + quad * 4 + r;
      int rB = rowB0 + quad * 4 + r;
      int col = hh * 64 + nt * 16 + L;
      y[((size_t)bb * 2048 + rA) * 1024 + col] = f2bf(oA[nt][r] * invA[r]);
      y[((size_t)bb * 2048 + rB) * 1024 + col] = f2bf(oB[nt][r] * invB[r]);
    }
  __builtin_amdgcn_s_waitcnt(0);
}

extern "C" void kernel_launch(void* const* d_in, const int* in_sizes, int n_in,
                              void* d_out, int out_size, void* d_ws, size_t ws_size,
                              hipStream_t stream) {
  const float* x      = (const float*)d_in[0];  // [2,2048,1024]
  const float* w_attn = (const float*)d_in[1];  // [1024,3072]
  const float* b_attn = (const float*)d_in[2];  // [3072]
  const float* w_proj = (const float*)d_in[3];  // [1024,1024]
  const float* b_proj = (const float*)d_in[4];  // [1024]
  float* out = (float*)d_out;                   // [2,2048,1024] fp32

  unsigned short* ws = (unsigned short*)d_ws;
  unsigned short* xb     = ws;                    //  4194304 [4096,1024]
  unsigned short* wattnT = xb + 4194304;          //  3145728 [3072,1024]
  unsigned short* wprojT = wattnT + 3145728;      //  1048576 [1024,1024]
  unsigned short* qkv    = wprojT + 1048576;      // 12582912 [3][32][2048][64] (v unused)
  unsigned short* yb     = qkv + 12582912;        //  4194304 [4096,1024]
  unsigned short* vt     = yb + 4194304;          //  4194304 [32][64][2048]

  // single cooperative launch: prep -> QKV -> attn -> proj with grid.sync
  void* args[] = {
    (void*)&x, (void*)&w_attn, (void*)&b_attn, (void*)&w_proj, (void*)&b_proj,
    (void*)&out, (void*)&xb, (void*)&wattnT, (void*)&wprojT, (void*)&qkv,
    (void*)&yb, (void*)&vt
  };
  hipError_t err = hipLaunchCooperativeKernel(
      reinterpret_cast<void*>(fused_all_kernel), dim3(512), dim3(256), args, 0, stream);
  if (err != hipSuccess) {
    (void)hipGetLastError();  // clear sticky error; fall back to 4-launch path
    prep_kernel<<<8192, 256, 0, stream>>>(x, w_attn, w_proj, xb, wattnT, wprojT);
    gemm_bt_kernel<128, 128><<<dim3(24, 32), 256, 0, stream>>>(xb, wattnT, b_attn, qkv, vt, 4096, 3072, 1024, 1);
    attn_kernel<<<dim3(512), 256, 0, stream>>>(qkv, vt, yb);
    gemm_bt_kernel<64, 64><<<dim3(16, 64), 256, 0, stream>>>(yb, wprojT, b_proj, out, nullptr, 4096, 1024, 1024, 0);
  }
}

// Round 13
// 177.451 us; speedup vs baseline: 2.2320x; 2.2320x over previous
//
#include <hip/hip_runtime.h>
#include <stdint.h>

// B=2, T=2048, C=1024, H=16, HD=64
// qkv ws layout: [3][B*H=32][T=2048][HD=64] bf16 (v region unused); vt: [32][64][2048] bf16

typedef short bf16x8 __attribute__((ext_vector_type(8)));
typedef float f32x4 __attribute__((ext_vector_type(4)));

__device__ inline unsigned short f2bf(float f) {
  union { float f; uint32_t u; } v; v.f = f;
  uint32_t u = v.u;
  u += 0x7FFFu + ((u >> 16) & 1u);   // round-to-nearest-even
  return (unsigned short)(u >> 16);
}

// pack two fp32 -> two bf16 in one dword — HW instruction (no builtin on gfx950, m240)
__device__ inline unsigned pkbf(float a, float b) {
  unsigned r;
  asm("v_cvt_pk_bf16_f32 %0, %1, %2" : "=v"(r) : "v"(a), "v"(b));
  return r;
}

// raw v_exp_f32 (2^x) without OCML range fixup; inputs bounded, -3e38 -> +0
__device__ inline float exp2_fast(float x) {
#if __has_builtin(__builtin_amdgcn_exp2f)
  return __builtin_amdgcn_exp2f(x);
#else
  float r; asm("v_exp_f32 %0, %1" : "=v"(r) : "v"(x)); return r;
#endif
}

// async global->LDS, 16B per lane, dest = lds base + lane*16
__device__ inline void load_lds16(const unsigned short* g, unsigned short* l) {
  __builtin_amdgcn_global_load_lds(
      (const __attribute__((address_space(1))) unsigned int*)(const void*)g,
      (__attribute__((address_space(3))) unsigned int*)(void*)l, 16, 0, 0);
}

// ---------- fused prep: cast x -> bf16, transpose+cast w_attn, w_proj ----------
// One launch instead of three (isolated effect ~-2.5us, r3<->r6 decomposition).
// blocks [0,4096): cast 1048576 float4 of x
// blocks [4096,7168): transpose w_attn [1024][3072] -> [3072][1024]
// blocks [7168,8192): transpose w_proj [1024][1024] -> [1024][1024]
__global__ __launch_bounds__(256) void prep_kernel(
    const float* __restrict__ x, const float* __restrict__ w_attn,
    const float* __restrict__ w_proj,
    unsigned short* __restrict__ xb, unsigned short* __restrict__ wattnT,
    unsigned short* __restrict__ wprojT) {
  __shared__ float tile[32][33];
  const int b = blockIdx.x, t = threadIdx.x;
  if (b < 4096) {
    int i = b * 256 + t;                      // < 1048576 always
    float4 f = reinterpret_cast<const float4*>(x)[i];
    ushort4 o;
    o.x = f2bf(f.x); o.y = f2bf(f.y); o.z = f2bf(f.z); o.w = f2bf(f.w);
    reinterpret_cast<ushort4*>(xb)[i] = o;
    return;
  }
  const float* in; unsigned short* out; int R, Cn, bx, by;
  if (b < 7168) {
    int bb = b - 4096;
    in = w_attn; out = wattnT; R = 1024; Cn = 3072;
    bx = (bb % 96) * 32; by = (bb / 96) * 32;
  } else {
    int bb = b - 7168;
    in = w_proj; out = wprojT; R = 1024; Cn = 1024;
    bx = (bb % 32) * 32; by = (bb / 32) * 32;
  }
  const int tx = t & 31, ty = t >> 5;         // block acts as (32,8)
  #pragma unroll
  for (int i = 0; i < 32; i += 8)
    tile[ty + i][tx] = in[(size_t)(by + ty + i) * Cn + bx + tx];
  __syncthreads();
  #pragma unroll
  for (int i = 0; i < 32; i += 8)
    out[(size_t)(bx + ty + i) * R + by + tx] = f2bf(tile[tx][ty + i]);
}

// ---------- bf16 MFMA GEMM: C[M,N] = A[M,K] * Bt[N,K]^T + bias ----------
// ROUND-3 PROVEN OPTIMUM of the 2-phase family (QKV 45.5us; 11 rounds of
// variants all >= this). LINEAR block decode is load-bearing: co-resident
// blocks bid,bid+1,bid+2 share the same A-panel (L2-hot) — the r10 XCD-rect
// decode cut chip FETCH 43% but broke the sharing and regressed 15%.
// Schedule: 2 LDS buffers, ONE barrier per K-step, vmcnt(0):
//   iter kt: vmcnt(0) [own tile-kt DMAs done]; barrier [all waves' DMAs done AND
//   buf^1's old tile consumed by everyone]; stage(kt+1 -> buf^1); compute(kt).
// Unpadded BMx32-short tiles, chunk swizzle pos = c ^ ((row>>1)&3).
// mode 0: write fp32 to out [M,N]
// mode 1: QKV scatter: q/k -> qkv layout (q scaled by 0.125*log2e), v -> vt[bh][d][t]
template<int BM, int BN>
__global__ __launch_bounds__(256) void gemm_bt_kernel(
    const unsigned short* __restrict__ A,
    const unsigned short* __restrict__ Bt,
    const float* __restrict__ bias,
    void* __restrict__ outp,
    unsigned short* __restrict__ vtp,
    int M, int N, int K, int mode) {
  constexpr int MT = BM / 32, NT = BN / 32;   // frags per wave per dim
  constexpr int RPWA = BM / 4, RPWB = BN / 4; // staged rows per wave
  constexpr int NJA = RPWA / 16, NJB = RPWB / 16;
  __shared__ unsigned short As[2][BM * 32];
  __shared__ unsigned short Bs[2][BN * 32];
  const int t = threadIdx.x;
  const int wave = t >> 6, lane = t & 63;
  const int L = lane & 15, quad = lane >> 4;
  const int wm = (wave >> 1) * (BM / 2), wn = (wave & 1) * (BN / 2);
  const int m0 = blockIdx.y * BM, n0 = blockIdx.x * BN;

  // DMA per-lane source mapping: 16 rows per instr, lane>>2 = row, lane&3 = stored pos
  const int drow = lane >> 2;
  const int dch  = (lane & 3) ^ ((drow >> 1) & 3);
  // frag read: logical chunk `quad` of row L stored at quad ^ ((L>>1)&3)
  const int foff = ((quad ^ ((L >> 1) & 3)) * 8);

  const unsigned short* Ab = A  + (size_t)(m0 + wave * RPWA + drow) * K + dch * 8;
  const unsigned short* Bb = Bt + (size_t)(n0 + wave * RPWB + drow) * K + dch * 8;

  f32x4 acc[MT][NT] = {};
  const int NK = K >> 5;

  // prologue: stage tile 0 -> buf 0
  #pragma unroll
  for (int j = 0; j < NJA; ++j)
    load_lds16(Ab + (size_t)j * 16 * K, &As[0][(wave * RPWA + j * 16) * 32]);
  #pragma unroll
  for (int j = 0; j < NJB; ++j)
    load_lds16(Bb + (size_t)j * 16 * K, &Bs[0][(wave * RPWB + j * 16) * 32]);

  int buf = 0;
  for (int kt = 0; kt < NK; ++kt) {
    asm volatile("" ::: "memory");
    __builtin_amdgcn_s_waitcnt(0x0F70);   // vmcnt(0): own DMAs for tile kt landed
    __builtin_amdgcn_s_barrier();         // everyone's DMAs landed; buf^1 consumed
    asm volatile("" ::: "memory");

    if (kt + 1 < NK) {                    // stage kt+1 into the other buffer
      #pragma unroll
      for (int j = 0; j < NJA; ++j)
        load_lds16(Ab + (size_t)j * 16 * K + (kt + 1) * 32,
                   &As[buf ^ 1][(wave * RPWA + j * 16) * 32]);
      #pragma unroll
      for (int j = 0; j < NJB; ++j)
        load_lds16(Bb + (size_t)j * 16 * K + (kt + 1) * 32,
                   &Bs[buf ^ 1][(wave * RPWB + j * 16) * 32]);
    }

    bf16x8 af[MT], bf[NT];
    #pragma unroll
    for (int mt = 0; mt < MT; ++mt)
      af[mt] = *reinterpret_cast<const bf16x8*>(&As[buf][(wm + mt * 16 + L) * 32 + foff]);
    #pragma unroll
    for (int nt = 0; nt < NT; ++nt)
      bf[nt] = *reinterpret_cast<const bf16x8*>(&Bs[buf][(wn + nt * 16 + L) * 32 + foff]);
    __builtin_amdgcn_s_setprio(1);
    #pragma unroll
    for (int mt = 0; mt < MT; ++mt)
      #pragma unroll
      for (int nt = 0; nt < NT; ++nt)
        acc[mt][nt] = __builtin_amdgcn_mfma_f32_16x16x32_bf16(af[mt], bf[nt], acc[mt][nt], 0, 0, 0);
    __builtin_amdgcn_s_setprio(0);
    buf ^= 1;
  }

  if (mode == 0) {
    float* out = (float*)outp;
    #pragma unroll
    for (int mt = 0; mt < MT; ++mt)
      #pragma unroll
      for (int nt = 0; nt < NT; ++nt) {
        int col = n0 + wn + nt * 16 + L;
        float b = bias[col];
        #pragma unroll
        for (int r = 0; r < 4; ++r) {
          int row = m0 + wm + mt * 16 + quad * 4 + r;
          out[(size_t)row * N + col] = acc[mt][nt][r] + b;
        }
      }
  } else {
    unsigned short* qkv = (unsigned short*)outp;  // [3][32][2048][64]
    #pragma unroll
    for (int mt = 0; mt < MT; ++mt)
      #pragma unroll
      for (int nt = 0; nt < NT; ++nt) {
        int col = n0 + wn + nt * 16 + L;          // 0..3071
        int sel = col >> 10, cc = col & 1023;
        int h = cc >> 6, d = cc & 63;
        float b = bias[col];
        // fold 1/sqrt(64) * log2(e) into q so attention uses exp2 directly
        float sc = (sel == 0) ? 0.18033688011112042f : 1.0f;
        #pragma unroll
        for (int r = 0; r < 4; ++r) {
          int row = m0 + wm + mt * 16 + quad * 4 + r;  // 0..4095
          int bb = row >> 11, tt = row & 2047;
          float val = (acc[mt][nt][r] + b) * sc;
          if (sel == 2) {
            // v -> vt[bh][d][t]  (fused V transpose)
            vtp[((size_t)(bb * 16 + h) * 64 + d) * 2048 + tt] = f2bf(val);
          } else {
            qkv[(((size_t)sel * 32 + (size_t)(bb * 16 + h)) * 2048 + tt) * 64 + d] = f2bf(val);
          }
        }
      }
  }
}

// ---------- flash attention v5 (round-1/3 best-measured config) ----------
// Softmax VALU diet: HW v_cvt_pk_bf16_f32, raw v_exp_f32, setprio around MFMA.
// Pair fold-balance + XCD-aware decode: all 16 pair-blocks of a bh share one mod-8
// residue class -> same XCD L2 caches that bh's K/V (cuts HBM re-fetch ~8x).
// S^T via swapped MFMA operands; 3-buffer K/V pipeline, single barrier per tile.
__global__ __launch_bounds__(256) void attn_kernel(
    const unsigned short* __restrict__ qkv,
    const unsigned short* __restrict__ vt,
    unsigned short* __restrict__ y) {
  __shared__ unsigned short Ks[3][64 * 64];  // [key][d], swizzled chunks
  __shared__ unsigned short Vs[3][64 * 64];  // [d][key], swizzled chunks
  __shared__ unsigned short Ps[4][32][72];   // per-wave P[qrow][key]: rows 0-15 A, 16-31 B

  const int t = threadIdx.x;
  const int wave = t >> 6, lane = t & 63;
  const int L = lane & 15, quad = lane >> 4;
  // XCD-aware decode: residue class (b&7) -> XCD; 4 bh per class x 16 pairs
  const int b = blockIdx.x;
  const int bh = (b & 7) * 4 + ((b >> 3) & 3);
  const int pi = b >> 5;                // pair index 0..15
  const int tA = pi, tB = 31 - pi;      // 64-row q-tile indices
  const int rowA0 = tA * 64 + wave * 16;
  const int rowB0 = tB * 64 + wave * 16;
  const int ntiles = tB + 1;

  const unsigned short* qb  = qkv + ((size_t)bh * 2048) * 64;
  const unsigned short* kb  = qkv + ((size_t)(32 + bh) * 2048) * 64;
  const unsigned short* vtb = vt + (size_t)bh * 64 * 2048;

  // DMA per-lane constants: 8 rows (128B each) per instruction
  const int drow = lane >> 3;           // 0..7
  const int dch  = (lane & 7) ^ drow;   // source chunk (xor swizzle)
  // frag-read swizzle offsets: chunk c of row r stored at c^(r&7)
  const int fo0 = ((quad ^ (L & 7)) * 8);
  const int fo1 = (((quad + 4) ^ (L & 7)) * 8);

  // Q fragments (A/B-operand layout, direct from global, resident all kernel)
  bf16x8 qfA[2], qfB[2];
  #pragma unroll
  for (int h = 0; h < 2; ++h) {
    qfA[h] = *reinterpret_cast<const bf16x8*>(qb + (size_t)(rowA0 + L) * 64 + h * 32 + quad * 8);
    qfB[h] = *reinterpret_cast<const bf16x8*>(qb + (size_t)(rowB0 + L) * 64 + h * 32 + quad * 8);
  }

  f32x4 oA[4] = {}, oB[4] = {};
  float rsA = 0.f, rsB = 0.f;

  // prologue: stage tile 0 -> buf 0 (4 DMA instrs per wave per stage)
  {
    #pragma unroll
    for (int j = 0; j < 2; ++j) {
      int r0 = wave * 16 + j * 8;
      load_lds16(kb  + (size_t)(0 + r0 + drow) * 64 + dch * 8, &Ks[0][r0 * 64]);
      load_lds16(vtb + (size_t)(r0 + drow) * 2048 + 0 + dch * 8, &Vs[0][r0 * 64]);
    }
  }

  int buf = 0;
  for (int kt = 0; kt < ntiles; ++kt) {
    // stage kt+1 (clamped dummy on last iter keeps vmcnt accounting uniform)
    const int nkt = (kt + 1 < ntiles) ? kt + 1 : ntiles - 1;
    const int nbuf = (buf == 2) ? 0 : buf + 1;
    {
      const int kg = nkt * 64;
      #pragma unroll
      for (int j = 0; j < 2; ++j) {
        int r0 = wave * 16 + j * 8;
        load_lds16(kb  + (size_t)(kg + r0 + drow) * 64 + dch * 8, &Ks[nbuf][r0 * 64]);
        load_lds16(vtb + (size_t)(r0 + drow) * 2048 + kg + dch * 8, &Vs[nbuf][r0 * 64]);
      }
    }
    asm volatile("" ::: "memory");
    __builtin_amdgcn_s_waitcnt(0x0F74);   // vmcnt(4): tile kt's 4 DMAs done; kt+1 in flight
    __builtin_amdgcn_s_barrier();
    asm volatile("" ::: "memory");

    const bool actA = (kt <= tA);

    // ---- S^T = K Q^T : D[m=key][n=qrow] (A=K-frag, B=Q-frag) ----
    bf16x8 kf[4][2];
    #pragma unroll
    for (int nt = 0; nt < 4; ++nt) {
      kf[nt][0] = *reinterpret_cast<const bf16x8*>(&Ks[buf][(nt * 16 + L) * 64 + fo0]);
      kf[nt][1] = *reinterpret_cast<const bf16x8*>(&Ks[buf][(nt * 16 + L) * 64 + fo1]);
    }

    f32x4 sB[4] = {};
    __builtin_amdgcn_s_setprio(1);
    #pragma unroll
    for (int nt = 0; nt < 4; ++nt) {
      sB[nt] = __builtin_amdgcn_mfma_f32_16x16x32_bf16(kf[nt][0], qfB[0], sB[nt], 0, 0, 0);
      sB[nt] = __builtin_amdgcn_mfma_f32_16x16x32_bf16(kf[nt][1], qfB[1], sB[nt], 0, 0, 0);
    }
    __builtin_amdgcn_s_setprio(0);
    if (kt == tB) {  // diagonal mask: key > qrow -> -inf
      #pragma unroll
      for (int nt = 0; nt < 4; ++nt) {
        int key0 = kt * 64 + nt * 16 + quad * 4;
        int qr = rowB0 + L;
        #pragma unroll
        for (int r = 0; r < 4; ++r)
          if (key0 + r > qr) sB[nt][r] = -3.0e38f;
      }
    }
    #pragma unroll
    for (int nt = 0; nt < 4; ++nt) {
      float p0 = exp2_fast(sB[nt][0]), p1 = exp2_fast(sB[nt][1]);
      float p2 = exp2_fast(sB[nt][2]), p3 = exp2_fast(sB[nt][3]);
      rsB += (p0 + p1) + (p2 + p3);
      uint2 pk;
      pk.x = pkbf(p0, p1);
      pk.y = pkbf(p2, p3);
      *reinterpret_cast<uint2*>(&Ps[wave][16 + L][nt * 16 + quad * 4]) = pk;
    }

    if (actA) {
      f32x4 sA[4] = {};
      __builtin_amdgcn_s_setprio(1);
      #pragma unroll
      for (int nt = 0; nt < 4; ++nt) {
        sA[nt] = __builtin_amdgcn_mfma_f32_16x16x32_bf16(kf[nt][0], qfA[0], sA[nt], 0, 0, 0);
        sA[nt] = __builtin_amdgcn_mfma_f32_16x16x32_bf16(kf[nt][1], qfA[1], sA[nt], 0, 0, 0);
      }
      __builtin_amdgcn_s_setprio(0);
      if (kt == tA) {
        #pragma unroll
        for (int nt = 0; nt < 4; ++nt) {
          int key0 = kt * 64 + nt * 16 + quad * 4;
          int qr = rowA0 + L;
          #pragma unroll
          for (int r = 0; r < 4; ++r)
            if (key0 + r > qr) sA[nt][r] = -3.0e38f;
        }
      }
      #pragma unroll
      for (int nt = 0; nt < 4; ++nt) {
        float p0 = exp2_fast(sA[nt][0]), p1 = exp2_fast(sA[nt][1]);
        float p2 = exp2_fast(sA[nt][2]), p3 = exp2_fast(sA[nt][3]);
        rsA += (p0 + p1) + (p2 + p3);
        uint2 pk;
        pk.x = pkbf(p0, p1);
        pk.y = pkbf(p2, p3);
        *reinterpret_cast<uint2*>(&Ps[wave][L][nt * 16 + quad * 4]) = pk;
      }
    }

    // ---- O += P V ----  (P in A-layout directly from Ps[qrow][key])
    bf16x8 vf[4][2];
    #pragma unroll
    for (int nt = 0; nt < 4; ++nt) {
      vf[nt][0] = *reinterpret_cast<const bf16x8*>(&Vs[buf][(nt * 16 + L) * 64 + fo0]);
      vf[nt][1] = *reinterpret_cast<const bf16x8*>(&Vs[buf][(nt * 16 + L) * 64 + fo1]);
    }
    bf16x8 pb0 = *reinterpret_cast<const bf16x8*>(&Ps[wave][16 + L][quad * 8]);
    bf16x8 pb1 = *reinterpret_cast<const bf16x8*>(&Ps[wave][16 + L][32 + quad * 8]);
    __builtin_amdgcn_s_setprio(1);
    #pragma unroll
    for (int nt = 0; nt < 4; ++nt) {
      oB[nt] = __builtin_amdgcn_mfma_f32_16x16x32_bf16(pb0, vf[nt][0], oB[nt], 0, 0, 0);
      oB[nt] = __builtin_amdgcn_mfma_f32_16x16x32_bf16(pb1, vf[nt][1], oB[nt], 0, 0, 0);
    }
    __builtin_amdgcn_s_setprio(0);
    if (actA) {
      bf16x8 pa0 = *reinterpret_cast<const bf16x8*>(&Ps[wave][L][quad * 8]);
      bf16x8 pa1 = *reinterpret_cast<const bf16x8*>(&Ps[wave][L][32 + quad * 8]);
      __builtin_amdgcn_s_setprio(1);
      #pragma unroll
      for (int nt = 0; nt < 4; ++nt) {
        oA[nt] = __builtin_amdgcn_mfma_f32_16x16x32_bf16(pa0, vf[nt][0], oA[nt], 0, 0, 0);
        oA[nt] = __builtin_amdgcn_mfma_f32_16x16x32_bf16(pa1, vf[nt][1], oA[nt], 0, 0, 0);
      }
      __builtin_amdgcn_s_setprio(0);
    }
    buf = nbuf;
  }

  // ---- epilogue: reduce l across quads (rows live on L), fetch per-output-row via shfl ----
  float a = rsA; a += __shfl_xor(a, 16, 64); a += __shfl_xor(a, 32, 64);
  float b2 = rsB; b2 += __shfl_xor(b2, 16, 64); b2 += __shfl_xor(b2, 32, 64);
  float invA[4], invB[4];
  #pragma unroll
  for (int r = 0; r < 4; ++r) {
    invA[r] = 1.0f / __shfl(a, quad * 4 + r, 64);
    invB[r] = 1.0f / __shfl(b2, quad * 4 + r, 64);
  }
  const int bb = bh >> 4, hh = bh & 15;
  #pragma unroll
  for (int nt = 0; nt < 4; ++nt)
    #pragma unroll
    for (int r = 0; r < 4; ++r) {
      int rA = rowA0 + quad * 4 + r;
      int rB = rowB0 + quad * 4 + r;
      int col = hh * 64 + nt * 16 + L;
      y[((size_t)bb * 2048 + rA) * 1024 + col] = f2bf(oA[nt][r] * invA[r]);
      y[((size_t)bb * 2048 + rB) * 1024 + col] = f2bf(oB[nt][r] * invB[r]);
    }
  // drain outstanding dummy DMAs before LDS dealloc at wave end
  __builtin_amdgcn_s_waitcnt(0);
}

extern "C" void kernel_launch(void* const* d_in, const int* in_sizes, int n_in,
                              void* d_out, int out_size, void* d_ws, size_t ws_size,
                              hipStream_t stream) {
  const float* x      = (const float*)d_in[0];  // [2,2048,1024]
  const float* w_attn = (const float*)d_in[1];  // [1024,3072]
  const float* b_attn = (const float*)d_in[2];  // [3072]
  const float* w_proj = (const float*)d_in[3];  // [1024,1024]
  const float* b_proj = (const float*)d_in[4];  // [1024]
  float* out = (float*)d_out;                   // [2,2048,1024] fp32

  unsigned short* ws = (unsigned short*)d_ws;
  unsigned short* xb     = ws;                    //  4194304 [4096,1024]
  unsigned short* wattnT = xb + 4194304;          //  3145728 [3072,1024]
  unsigned short* wprojT = wattnT + 3145728;      //  1048576 [1024,1024]
  unsigned short* qkv    = wprojT + 1048576;      // 12582912 [3][32][2048][64] (v unused)
  unsigned short* yb     = qkv + 12582912;        //  4194304 [4096,1024]
  unsigned short* vt     = yb + 4194304;          //  4194304 [32][64][2048]

  // fused prep: cast x + transpose both weight matrices (one launch)
  prep_kernel<<<8192, 256, 0, stream>>>(x, w_attn, w_proj, xb, wattnT, wprojT);

  // QKV: M=4096, N=3072, K=1024; 128^2 tiles, grid (24,32) LINEAR decode
  // (round-3 proven optimum: 45.5us; linear decode preserves A-panel sharing)
  gemm_bt_kernel<128, 128><<<dim3(24, 32), 256, 0, stream>>>(xb, wattnT, b_attn, qkv, vt, 4096, 3072, 1024, 1);
  // attention (fold-balanced, XCD-grouped, 3-buffer pipelined)
  attn_kernel<<<dim3(512), 256, 0, stream>>>(qkv, vt, yb);
  // proj: M=4096, N=1024, K=1024; 64^2 tiles, grid (16,64) linear (round-3 config)
  gemm_bt_kernel<64, 64><<<dim3(16, 64), 256, 0, stream>>>(yb, wprojT, b_proj, out, nullptr, 4096, 1024, 1024, 0);
}